// Round 3
// baseline (1267.537 us; speedup 1.0000x reference)
//
#include <hip/hip_runtime.h>
#include <stdint.h>
#include <stddef.h>

// CharPredictorMultirateFFN on MI355X (gfx950).
// Pipeline: gather(+pad) -> conv_w transpose -> lin_w transpose -> conv GEMM (fp16 MFMA)
//           -> linear GEMM + fused softmax.
//
// R9: fix R8's latency exposure. R8 proved B-from-L2 locality works (FETCH 1.07GB->349MB)
// but depth-1 prefetch left ~120 cyc L2-latency stall per tap (MfmaUtil 44.5 = MFMA
// floor 525us / 1180us). R9: 3 rotating B register buffers (static k%3 indexing),
// issue B[k+2] before computing tap k -> issue-to-consume gap ~2 tap rounds (300-450
// wall cyc) > 225 cyc L2 latency. A slab double-buffered (18 KB) so staging for j+1
// overlaps taps of j; barriers 32 -> 16 per block. LDS traffic is A-only (~4.3 MB/blk,
// well under the 85 B/cyc ds_read ceiling that bound R6 at 82 B/cyc). launch_bounds
// (256,3) pins occupancy at 3 waves/SIMD (VGPR<=106 + 64 acc AGPR). nb-XCD-pinned
// swizzle, A XOR-swizzle (0 conflicts), epilogue: all R5/R6/R8-verified.

typedef _Float16 f16;
typedef __attribute__((ext_vector_type(8))) _Float16 f16x8;
typedef __attribute__((ext_vector_type(4))) float f32x4;

#define SP 2063  // padded rows per batch item: 15 + 2048

__device__ __forceinline__ void gl2lds16(const void* g, void* l) {
  __builtin_amdgcn_global_load_lds((const __attribute__((address_space(1))) void*)g,
                                   (__attribute__((address_space(3))) void*)l, 16, 0, 0);
}

// ---------------- gather: emb_table[seq] -> f16 padded buffer [32][2063][512] --------
__global__ __launch_bounds__(256) void k_gather(const int* __restrict__ seq,
                                                const float* __restrict__ tab,
                                                f16* __restrict__ embp) {
  int row = blockIdx.x * 4 + (threadIdx.x >> 6);   // 0 .. 66015
  int lane = threadIdx.x & 63;
  int b = row / SP;
  int r = row - b * SP;
  f16* dst = embp + (size_t)row * 512 + lane * 8;
  if (r < 15) {
    f16x8 z = {(f16)0, (f16)0, (f16)0, (f16)0, (f16)0, (f16)0, (f16)0, (f16)0};
    *(f16x8*)dst = z;
  } else {
    int idx = seq[b * 2048 + (r - 15)];
    const float4* src = (const float4*)(tab + (size_t)idx * 512 + lane * 8);
    float4 v0 = src[0], v1 = src[1];
    f16x8 o;
    o[0] = (f16)v0.x; o[1] = (f16)v0.y; o[2] = (f16)v0.z; o[3] = (f16)v0.w;
    o[4] = (f16)v1.x; o[5] = (f16)v1.y; o[6] = (f16)v1.z; o[7] = (f16)v1.w;
    *(f16x8*)dst = o;
  }
}

// ---------------- conv_w [H][E][K] f32 -> wt2 [256 jk][1024 h][32 e5] f16 ------------
// jk = j*16 + k ; e = j*32 + e5. Coalesced read of one h-row into LDS, transpose out.
__global__ __launch_bounds__(256) void k_twc(const float* __restrict__ cw,
                                             f16* __restrict__ wt2) {
  __shared__ f16 tile[8192];          // [e][k] in source order (16 KB)
  int h = blockIdx.x;                 // 1024 blocks
  const float4* src = (const float4*)(cw + (size_t)h * 8192);
#pragma unroll
  for (int i = 0; i < 8; ++i) {
    int o = i * 256 + threadIdx.x;    // float4 index, fully coalesced
    float4 v = src[o];
    f16* d = tile + o * 4;
    d[0] = (f16)v.x; d[1] = (f16)v.y; d[2] = (f16)v.z; d[3] = (f16)v.w;
  }
  __syncthreads();
  // thread t = j*16+k writes 32 halves: wt2[(t*1024 + h)*32 + e5] = tile[(j*32+e5)*16 + k]
  int j = threadIdx.x >> 4, k = threadIdx.x & 15;
  f16* dst = wt2 + ((size_t)threadIdx.x * 1024 + h) * 32;
#pragma unroll
  for (int c8 = 0; c8 < 4; ++c8) {
    f16x8 v;
#pragma unroll
    for (int t = 0; t < 8; ++t) v[t] = tile[((j * 32 + c8 * 8 + t) << 4) | k];
    *(f16x8*)(dst + c8 * 8) = v;
  }
}

// ---------------- lin_w [V][F] f32 -> lt2 [48 fblk][256 v][32] f16 -------------------
__global__ __launch_bounds__(256) void k_twl(const float* __restrict__ lw,
                                             f16* __restrict__ lt2) {
  int o = blockIdx.x * 256 + threadIdx.x;  // 393216 outputs
  int f5 = o & 31;
  int v = (o >> 5) & 255;
  int kb = o >> 13;            // 0..47
  int f = (kb << 5) | f5;
  lt2[o] = (f16)lw[(size_t)v * 1536 + f];
}

// ---------------- conv GEMM: [65536 x 8192] x [8192 x 1024] -> relu -> f16 -----------
// 128x128 block, 4 waves (2x2 of 64x64 wave tiles, each 4x4 of 16x16 MFMA tiles).
// A slab dbuf (18 KB) in LDS; B fragments straight from XCD-local L2, 3 rotating
// register buffers, depth-2 prefetch. 1 barrier per e-block (16 per block).
__global__ __launch_bounds__(256, 3) void k_conv(const f16* __restrict__ embp,
                                                 const f16* __restrict__ wt2,
                                                 const float* __restrict__ cb,
                                                 f16* __restrict__ cout) {
  __shared__ __align__(16) f16 Asl[2 * 144 * 32];   // 18 KB A slab double buffer
  // nb-XCD-pinned swizzle: bid&7 -> XCD -> fixed 128-col B panel (2 MB, L2-resident).
  int bid = blockIdx.x;
  int nb = bid & 7;
  int mb = bid >> 3;             // 0..511
  int n0 = nb << 7, m0 = mb << 7;
  int b = m0 >> 11, t0 = m0 & 2047;
  int tid = threadIdx.x, lane = tid & 63, wave = tid >> 6;
  int wr = wave >> 1, wc = wave & 1;
  int fr = lane & 15, q = lane >> 4;
  int prl = lane >> 2, pc = lane & 3;   // staging: row-within-64-group, phys chunk

  // A stage sources. c=0,1: rows c*64 + wave*16 + prl (full 128 rows).
  // c=2: rows 128 + prl, ALL 4 waves redundantly (same data, benign WAW).
  // Source fetches logical chunk pc ^ ((row>>1)&3) (XOR-swizzled layout).
  const f16* gA[3];
#pragma unroll
  for (int c = 0; c < 2; ++c) {
    int pr = c * 64 + wave * 16 + prl;
    int clog = pc ^ ((pr >> 1) & 3);
    gA[c] = embp + (size_t)(b * SP + t0 + pr) * 512 + clog * 8;
  }
  {
    int pr = 128 + prl;
    int clog = pc ^ ((pr >> 1) & 3);
    gA[2] = embp + (size_t)(b * SP + t0 + pr) * 512 + clog * 8;
  }

  // B fragment base: lane (fr,q) reads h = n0 + wc*64 + jj*16 + fr, e-chunk q.
  // Per jj this is a contiguous 1 KB wave read (fr*64B + q*16B) -> fully coalesced.
  const f16* gB = wt2 + (size_t)(n0 + wc * 64 + fr) * 32 + q * 8;

  f32x4 zero = {0.f, 0.f, 0.f, 0.f};
  f32x4 acc[4][4];
#pragma unroll
  for (int i = 0; i < 4; ++i)
#pragma unroll
    for (int jj = 0; jj < 4; ++jj) acc[i][jj] = zero;

  f16x8 bb[3][4];                      // 3 rotating B tap buffers (static indexing)

  // prologue: stage A slab for j=0, load B taps 0,1
#pragma unroll
  for (int c = 0; c < 2; ++c)
    gl2lds16(gA[c], Asl + c * 2048 + wave * 512);
  gl2lds16(gA[2], Asl + 4096);
#pragma unroll
  for (int jj = 0; jj < 4; ++jj) bb[0][jj] = *(const f16x8*)(gB + jj * 512);
#pragma unroll
  for (int jj = 0; jj < 4; ++jj) bb[1][jj] = *(const f16x8*)(gB + 32768 + jj * 512);
  __syncthreads();                     // vmcnt(0): A slab 0 (and bb0,bb1) landed

#pragma unroll 1
  for (int j = 0; j < 16; ++j) {
    const f16* Ab = Asl + (j & 1) * 4608;
    int sbn = ((j + 1) & 1) * 4608;
#pragma unroll
    for (int k = 0; k < 16; ++k) {
      // depth-2 B prefetch: issue tap k+2 of this e-block
      if (k <= 13) {
        const f16* p = gB + (size_t)(j * 16 + k + 2) * 32768;
#pragma unroll
        for (int jj = 0; jj < 4; ++jj) bb[(k + 2) % 3][jj] = *(const f16x8*)(p + jj * 512);
      }
      // A-stage for j+1, issued after tap0's B prefetch so B waits don't chain on it
      if (k == 0 && j < 15) {
#pragma unroll
        for (int c = 0; c < 2; ++c)
          gl2lds16(gA[c] + (j + 1) * 32, Asl + sbn + c * 2048 + wave * 512);
        gl2lds16(gA[2] + (j + 1) * 32, Asl + sbn + 4096);
      }
      // compute tap k with bb[k%3]
      {
        int aswz = ((k + fr) >> 1) & 3;
        const f16* ap = Ab + (size_t)(k + wr * 64 + fr) * 32 + ((q ^ aswz) << 3);
#pragma unroll
        for (int i = 0; i < 4; ++i) {
          f16x8 af = *(const f16x8*)(ap + i * 512);
#pragma unroll
          for (int jj = 0; jj < 4; ++jj)
            acc[i][jj] = __builtin_amdgcn_mfma_f32_16x16x32_f16(af, bb[k % 3][jj], acc[i][jj], 0, 0, 0);
        }
      }
    }
    // prefetch next e-block's taps 0,1 (land during the barrier drain)
    if (j < 15) {
      const f16* p0 = gB + (size_t)((j + 1) * 16) * 32768;
      const f16* p1 = p0 + 32768;
#pragma unroll
      for (int jj = 0; jj < 4; ++jj) bb[0][jj] = *(const f16x8*)(p0 + jj * 512);
#pragma unroll
      for (int jj = 0; jj < 4; ++jj) bb[1][jj] = *(const f16x8*)(p1 + jj * 512);
    }
    __syncthreads();   // drains A[j+1] gl2lds (+ bb0,bb1); releases Asl[(j+1)&1] writes
  }

  // epilogue: bias + relu + f16 store. C/D: col=lane&15 (n), row=(lane>>4)*4+reg (m)
  int col = lane & 15, rq = (lane >> 4) << 2;
  int mbase = m0 + wr * 64 + rq;
  int nbase = n0 + wc * 64 + col;
#pragma unroll
  for (int jj = 0; jj < 4; ++jj) {
    int h = nbase + jj * 16;
    float bias = cb[h];
#pragma unroll
    for (int i = 0; i < 4; ++i) {
      int m = mbase + i * 16;
#pragma unroll
      for (int rg = 0; rg < 4; ++rg) {
        float v = acc[i][jj][rg] + bias;
        v = v > 0.f ? v : 0.f;
        cout[(size_t)(m + rg) * 1024 + h] = (f16)v;
      }
    }
  }
}

// ---------------- linear GEMM [65536 x 1536] x [1536 x 256] + fused softmax ----------
__global__ __launch_bounds__(256) void k_lin(const f16* __restrict__ embp,
                                             const f16* __restrict__ cout,
                                             const f16* __restrict__ lt2,
                                             const float* __restrict__ lb,
                                             float* __restrict__ out) {
  __shared__ __align__(16) char smem[32 * 261 * 4];  // Ls overlays As|Bs
  __shared__ float pmax[4][32], psum[4][32], mrow[32], rinv[32];
  f16* As = (f16*)smem;             // [64][32]   4 KB
  f16* Bs = (f16*)(smem + 4096);    // [256][32] 16 KB
  float* Ls = (float*)smem;         // [32][261] f32 epilogue logits
  int m0 = blockIdx.x << 6;
  int b = m0 >> 11, t0 = m0 & 2047;
  int tid = threadIdx.x, lane = tid & 63, wave = tid >> 6;
  int sr = lane >> 2, sc = (lane & 3) << 3;
  const f16* gAe = embp + (size_t)(b * SP + 15 + t0 + wave * 16 + sr) * 512 + sc;
  const f16* gAc = cout + (size_t)(m0 + wave * 16 + sr) * 1024 + sc;
  f16* lA = As + wave * 512;
  int fr = lane & 15, fq = (lane >> 4) << 3;
  f32x4 zero = {0.f, 0.f, 0.f, 0.f};
  f32x4 acc[4][4];
#pragma unroll
  for (int i = 0; i < 4; ++i)
#pragma unroll
    for (int j = 0; j < 4; ++j) acc[i][j] = zero;

  for (int kb = 0; kb < 48; ++kb) {
    if (kb < 16) gl2lds16(gAe + kb * 32, lA);
    else         gl2lds16(gAc + (kb - 16) * 32, lA);
#pragma unroll
    for (int jj = 0; jj < 4; ++jj) {
      int c = wave * 4 + jj;
      gl2lds16(lt2 + (size_t)kb * 8192 + (c * 16 + sr) * 32 + sc, Bs + c * 512);
    }
    __syncthreads();
    f16x8 af[4], bf[4];
#pragma unroll
    for (int i = 0; i < 4; ++i)
      af[i] = *(const f16x8*)(As + (i * 16 + fr) * 32 + fq);
#pragma unroll
    for (int j = 0; j < 4; ++j)
      bf[j] = *(const f16x8*)(Bs + (wave * 64 + j * 16 + fr) * 32 + fq);
#pragma unroll
    for (int i = 0; i < 4; ++i)
#pragma unroll
      for (int j = 0; j < 4; ++j)
        acc[i][j] = __builtin_amdgcn_mfma_f32_16x16x32_f16(af[i], bf[j], acc[i][j], 0, 0, 0);
    __syncthreads();
  }

  // softmax epilogue, two 32-row halves. Ls stride 261 (coprime with 32).
  int col = lane & 15, rq = (lane >> 4) << 2;
  for (int hf = 0; hf < 2; ++hf) {
    __syncthreads();
#pragma unroll
    for (int j = 0; j < 4; ++j) {
      int v = wave * 64 + j * 16 + col;
      float bias = lb[v];
#pragma unroll
      for (int i = 0; i < 2; ++i) {
        int rloc = i * 16 + rq;
        int ig = hf * 2 + i;
#pragma unroll
        for (int rg = 0; rg < 4; ++rg)
          Ls[(rloc + rg) * 261 + v] = acc[ig][j][rg] + bias;
      }
    }
    __syncthreads();
    if (tid < 128) {
      int r = tid & 31, qd = tid >> 5;
      const float* rowp = Ls + r * 261 + qd * 64;
      float pm = -1e30f;
#pragma unroll 8
      for (int c = 0; c < 64; ++c) pm = fmaxf(pm, rowp[c]);
      pmax[qd][r] = pm;
    }
    __syncthreads();
    if (tid < 32)
      mrow[tid] = fmaxf(fmaxf(pmax[0][tid], pmax[1][tid]), fmaxf(pmax[2][tid], pmax[3][tid]));
    __syncthreads();
    if (tid < 128) {
      int r = tid & 31, qd = tid >> 5;
      const float* rowp = Ls + r * 261 + qd * 64;
      float mr = mrow[r], ps = 0.f;
#pragma unroll 8
      for (int c = 0; c < 64; ++c) ps += __expf(rowp[c] - mr);
      psum[qd][r] = ps;
    }
    __syncthreads();
    if (tid < 32)
      rinv[tid] = 1.f / (psum[0][tid] + psum[1][tid] + psum[2][tid] + psum[3][tid]);
    __syncthreads();
    float* obase = out + (size_t)(m0 + hf * 32) * 256 + tid;
#pragma unroll 4
    for (int r = 0; r < 32; ++r)
      obase[(size_t)r * 256] = __expf(Ls[r * 261 + tid] - mrow[r]) * rinv[r];
  }
}

extern "C" void kernel_launch(void* const* d_in, const int* in_sizes, int n_in,
                              void* d_out, int out_size, void* d_ws, size_t ws_size,
                              hipStream_t stream) {
  const int*   seq = (const int*)d_in[0];
  const float* tab = (const float*)d_in[1];
  const float* cw  = (const float*)d_in[2];
  const float* cb  = (const float*)d_in[3];
  const float* lw  = (const float*)d_in[4];
  const float* lb  = (const float*)d_in[5];
  float* out = (float*)d_out;
  char* ws = (char*)d_ws;
  // workspace layout (needs ~219.4 MB):
  f16* embp = (f16*)(ws);               //  67,600,384 B  [32*2063][512]
  f16* cout = (f16*)(ws + 67600384);    // 134,217,728 B  [65536][1024]
  f16* wt2  = (f16*)(ws + 201818112);   //  16,777,216 B  [256 jk][1024 h][32 e5]
  f16* lt2  = (f16*)(ws + 218595328);   //     786,432 B  [48][256][32]

  hipLaunchKernelGGL(k_gather, dim3(16504), dim3(256), 0, stream, seq, tab, embp);
  hipLaunchKernelGGL(k_twc,    dim3(1024),  dim3(256), 0, stream, cw, wt2);
  hipLaunchKernelGGL(k_twl,    dim3(1536),  dim3(256), 0, stream, lw, lt2);
  hipLaunchKernelGGL(k_conv,   dim3(4096),  dim3(256), 0, stream, embp, wt2, cb, cout);
  hipLaunchKernelGGL(k_lin,    dim3(1024),  dim3(256), 0, stream, embp, cout, lt2, lb, out);
}

// Round 4
// 1215.932 us; speedup vs baseline: 1.0424x; 1.0424x over previous
//
#include <hip/hip_runtime.h>
#include <stdint.h>
#include <stddef.h>

// CharPredictorMultirateFFN on MI355X (gfx950).
// Pipeline: gather(+pad) -> conv_w transpose -> lin_w transpose -> conv GEMM (fp16 MFMA)
//           -> linear GEMM + fused softmax.
//
// R10: revert to the R6 structure (best verified: 864 us, MfmaUtil 68.3) and enlarge
// the wave tile 64x64 -> 128x64. R8/R9 falsified the B-from-L2 branch (both 1180 us);
// R6's wall is LDS read BW (82 of 85 B/cyc ds_read_b128 ceiling). Bytes/FLOP scales as
// (WM+WN)/(WM*WN): 128x64 cuts LDS traffic 0.75x per FLOP (block 256x128, per-CU
// 170 -> 118 MB) and doubles MFMA per barrier drain (620 vs 312 cyc -> predicted util
// 81% by R6's measured overhead model). Everything else identical to R6: LDS-staged B
// in 4-tap groups, vmcnt(0)+syncthreads pairs, XOR swizzle (0 conflicts), mb-XCD
// swizzle, coalesced k_twc. LDS 50 KB; acc 128 AGPR -> ~2 blocks/CU.

typedef _Float16 f16;
typedef __attribute__((ext_vector_type(8))) _Float16 f16x8;
typedef __attribute__((ext_vector_type(4))) float f32x4;

#define SP 2063  // padded rows per batch item: 15 + 2048

__device__ __forceinline__ void gl2lds16(const void* g, void* l) {
  __builtin_amdgcn_global_load_lds((const __attribute__((address_space(1))) void*)g,
                                   (__attribute__((address_space(3))) void*)l, 16, 0, 0);
}

// ---------------- gather: emb_table[seq] -> f16 padded buffer [32][2063][512] --------
__global__ __launch_bounds__(256) void k_gather(const int* __restrict__ seq,
                                                const float* __restrict__ tab,
                                                f16* __restrict__ embp) {
  int row = blockIdx.x * 4 + (threadIdx.x >> 6);   // 0 .. 66015
  int lane = threadIdx.x & 63;
  int b = row / SP;
  int r = row - b * SP;
  f16* dst = embp + (size_t)row * 512 + lane * 8;
  if (r < 15) {
    f16x8 z = {(f16)0, (f16)0, (f16)0, (f16)0, (f16)0, (f16)0, (f16)0, (f16)0};
    *(f16x8*)dst = z;
  } else {
    int idx = seq[b * 2048 + (r - 15)];
    const float4* src = (const float4*)(tab + (size_t)idx * 512 + lane * 8);
    float4 v0 = src[0], v1 = src[1];
    f16x8 o;
    o[0] = (f16)v0.x; o[1] = (f16)v0.y; o[2] = (f16)v0.z; o[3] = (f16)v0.w;
    o[4] = (f16)v1.x; o[5] = (f16)v1.y; o[6] = (f16)v1.z; o[7] = (f16)v1.w;
    *(f16x8*)dst = o;
  }
}

// ---------------- conv_w [H][E][K] f32 -> wt2 [256 jk][1024 h][32 e5] f16 ------------
// jk = j*16 + k ; e = j*32 + e5. Coalesced read of one h-row into LDS, transpose out.
__global__ __launch_bounds__(256) void k_twc(const float* __restrict__ cw,
                                             f16* __restrict__ wt2) {
  __shared__ f16 tile[8192];          // [e][k] in source order (16 KB)
  int h = blockIdx.x;                 // 1024 blocks
  const float4* src = (const float4*)(cw + (size_t)h * 8192);
#pragma unroll
  for (int i = 0; i < 8; ++i) {
    int o = i * 256 + threadIdx.x;    // float4 index, fully coalesced
    float4 v = src[o];
    f16* d = tile + o * 4;
    d[0] = (f16)v.x; d[1] = (f16)v.y; d[2] = (f16)v.z; d[3] = (f16)v.w;
  }
  __syncthreads();
  // thread t = j*16+k writes 32 halves: wt2[(t*1024 + h)*32 + e5] = tile[(j*32+e5)*16 + k]
  int j = threadIdx.x >> 4, k = threadIdx.x & 15;
  f16* dst = wt2 + ((size_t)threadIdx.x * 1024 + h) * 32;
#pragma unroll
  for (int c8 = 0; c8 < 4; ++c8) {
    f16x8 v;
#pragma unroll
    for (int t = 0; t < 8; ++t) v[t] = tile[((j * 32 + c8 * 8 + t) << 4) | k];
    *(f16x8*)(dst + c8 * 8) = v;
  }
}

// ---------------- lin_w [V][F] f32 -> lt2 [48 fblk][256 v][32] f16 -------------------
__global__ __launch_bounds__(256) void k_twl(const float* __restrict__ lw,
                                             f16* __restrict__ lt2) {
  int o = blockIdx.x * 256 + threadIdx.x;  // 393216 outputs
  int f5 = o & 31;
  int v = (o >> 5) & 255;
  int kb = o >> 13;            // 0..47
  int f = (kb << 5) | f5;
  lt2[o] = (f16)lw[(size_t)v * 1536 + f];
}

// ---------------- conv GEMM: [65536 x 8192] x [8192 x 1024] -> relu -> f16 -----------
// 256x128 block, 4 waves (2x2: wr over M strips of 128, wc over N strips of 64).
// Each wave: 8x4 of 16x16 MFMA tiles (128x64), acc = 32 f32x4 (AGPR).
// j outer (16 e-blocks), 4 tap-groups of 4 taps. A slab (272 rows, 17.4 KB) staged
// once per j; per group 4 B tiles (32 KB) staged, one barrier-pair, 128 MFMA/wave.
__global__ __launch_bounds__(256) void k_conv(const f16* __restrict__ embp,
                                              const f16* __restrict__ wt2,
                                              const float* __restrict__ cb,
                                              f16* __restrict__ cout) {
  __shared__ __align__(16) f16 Asl[272 * 32];     // 17.4 KB A slab (rows 0..270 used)
  __shared__ __align__(16) f16 Bs[4 * 128 * 32];  // 32 KB: 4 B tap-tiles
  // XCD-pinned swizzle (R3/R5-verified): bid&7 -> XCD, n fastest within.
  int bid = blockIdx.x;                // 2048 blocks
  int x8 = bid & 7;
  int s = bid >> 3;                    // 0..255
  int nb = s & 7;
  int mb = ((s >> 3) << 3) | x8;       // 0..255
  int n0 = nb << 7, m0 = mb << 8;      // M block = 256 rows
  int b = m0 >> 11, t0 = m0 & 2047;    // 256 | 2048 -> no item straddle
  int tid = threadIdx.x, lane = tid & 63, wave = tid >> 6;
  int wr = wave >> 1, wc = wave & 1;
  int fr = lane & 15, q = lane >> 4;
  int prl = lane >> 2, pc = lane & 3;  // staging: row-within-64-group, phys chunk

  // A slab staging (5 calls x 1 KB per wave): c=0..3 cover rows 0..255
  // (pr = c*64 + wave*16 + prl); tail rows 256..271 staged redundantly by all
  // waves (same data, benign WAW; row 271 is never read). Source fetches logical
  // chunk pc ^ ((pr>>1)&3)  (XOR-swizzled layout, R2/R5-verified: 0 conflicts).
  const f16* gAs[5];
#pragma unroll
  for (int c = 0; c < 4; ++c) {
    int pr = c * 64 + wave * 16 + prl;
    int clog = pc ^ ((pr >> 1) & 3);
    gAs[c] = embp + (size_t)(b * SP + t0 + pr) * 512 + clog * 8;
  }
  {
    int pr = 256 + prl;
    int clog = pc ^ ((pr >> 1) & 3);
    gAs[4] = embp + (size_t)(b * SP + t0 + pr) * 512 + clog * 8;
  }
  // B tile staging (2 calls x 1 KB per wave per tile), same swizzle.
  const f16* gBs[2];
#pragma unroll
  for (int c = 0; c < 2; ++c) {
    int pr = c * 64 + wave * 16 + prl;
    int clog = pc ^ ((pr >> 1) & 3);
    gBs[c] = wt2 + (size_t)(n0 + pr) * 32 + clog * 8;
  }
  f16* lB0 = Bs + (wave * 16) * 32;

  int fqB = (q ^ ((fr >> 1) & 3)) << 3;         // B frag phys chunk (rows % 16 aligned)

  f32x4 zero = {0.f, 0.f, 0.f, 0.f};
  f32x4 acc[8][4];
#pragma unroll
  for (int i = 0; i < 8; ++i)
#pragma unroll
    for (int jj = 0; jj < 4; ++jj) acc[i][jj] = zero;

  for (int j = 0; j < 16; ++j) {
    // A slab for this e-block (once per j; previous group's trailing barrier
    // guarantees all waves are done reading the old slab)
#pragma unroll
    for (int c = 0; c < 4; ++c)
      gl2lds16(gAs[c] + j * 32, Asl + c * 2048 + wave * 512);
    gl2lds16(gAs[4] + j * 32, Asl + 8192);
    for (int g = 0; g < 4; ++g) {
      // stage 4 B tiles (taps g*4 .. g*4+3)
#pragma unroll
      for (int t = 0; t < 4; ++t) {
        size_t bOff = ((size_t)(j * 16 + g * 4 + t)) * 32768;
#pragma unroll
        for (int c = 0; c < 2; ++c)
          gl2lds16(gBs[c] + bOff, lB0 + t * 4096 + c * 2048);
      }
      __syncthreads();
#pragma unroll 2
      for (int t = 0; t < 4; ++t) {
        int k = g * 4 + t;
        // A frag: slab row = k + wr*128 + i*16 + fr ; swizzle incl. tap offset k
        // ((row>>1)&3 == ((k+fr)>>1)&3 since wr*128, i*16 are multiples of 8).
        int aswz = ((k + fr) >> 1) & 3;
        const f16* ap = Asl + (size_t)(k + wr * 128 + fr) * 32 + ((q ^ aswz) << 3);
        f16x8 bf[4];
#pragma unroll
        for (int jj = 0; jj < 4; ++jj)
          bf[jj] = *(const f16x8*)(Bs + t * 4096 + (wc * 64 + jj * 16 + fr) * 32 + fqB);
#pragma unroll
        for (int i = 0; i < 8; ++i) {
          f16x8 af = *(const f16x8*)(ap + i * 512);
#pragma unroll
          for (int jj = 0; jj < 4; ++jj)
            acc[i][jj] = __builtin_amdgcn_mfma_f32_16x16x32_f16(af, bf[jj], acc[i][jj], 0, 0, 0);
        }
      }
      __syncthreads();
    }
  }
  // epilogue: bias + relu + f16 store. C/D: col=lane&15 (n), row=(lane>>4)*4+reg (m)
  int col = lane & 15, rq = (lane >> 4) << 2;
  int mbase = m0 + wr * 128 + rq;
  int nbase = n0 + wc * 64 + col;
#pragma unroll
  for (int jj = 0; jj < 4; ++jj) {
    int h = nbase + jj * 16;
    float bias = cb[h];
#pragma unroll
    for (int i = 0; i < 8; ++i) {
      int m = mbase + i * 16;
#pragma unroll
      for (int rg = 0; rg < 4; ++rg) {
        float v = acc[i][jj][rg] + bias;
        v = v > 0.f ? v : 0.f;
        cout[(size_t)(m + rg) * 1024 + h] = (f16)v;
      }
    }
  }
}

// ---------------- linear GEMM [65536 x 1536] x [1536 x 256] + fused softmax ----------
__global__ __launch_bounds__(256) void k_lin(const f16* __restrict__ embp,
                                             const f16* __restrict__ cout,
                                             const f16* __restrict__ lt2,
                                             const float* __restrict__ lb,
                                             float* __restrict__ out) {
  __shared__ __align__(16) char smem[32 * 261 * 4];  // Ls overlays As|Bs
  __shared__ float pmax[4][32], psum[4][32], mrow[32], rinv[32];
  f16* As = (f16*)smem;             // [64][32]   4 KB
  f16* Bs = (f16*)(smem + 4096);    // [256][32] 16 KB
  float* Ls = (float*)smem;         // [32][261] f32 epilogue logits
  int m0 = blockIdx.x << 6;
  int b = m0 >> 11, t0 = m0 & 2047;
  int tid = threadIdx.x, lane = tid & 63, wave = tid >> 6;
  int sr = lane >> 2, sc = (lane & 3) << 3;
  const f16* gAe = embp + (size_t)(b * SP + 15 + t0 + wave * 16 + sr) * 512 + sc;
  const f16* gAc = cout + (size_t)(m0 + wave * 16 + sr) * 1024 + sc;
  f16* lA = As + wave * 512;
  int fr = lane & 15, fq = (lane >> 4) << 3;
  f32x4 zero = {0.f, 0.f, 0.f, 0.f};
  f32x4 acc[4][4];
#pragma unroll
  for (int i = 0; i < 4; ++i)
#pragma unroll
    for (int j = 0; j < 4; ++j) acc[i][j] = zero;

  for (int kb = 0; kb < 48; ++kb) {
    if (kb < 16) gl2lds16(gAe + kb * 32, lA);
    else         gl2lds16(gAc + (kb - 16) * 32, lA);
#pragma unroll
    for (int jj = 0; jj < 4; ++jj) {
      int c = wave * 4 + jj;
      gl2lds16(lt2 + (size_t)kb * 8192 + (c * 16 + sr) * 32 + sc, Bs + c * 512);
    }
    __syncthreads();
    f16x8 af[4], bf[4];
#pragma unroll
    for (int i = 0; i < 4; ++i)
      af[i] = *(const f16x8*)(As + (i * 16 + fr) * 32 + fq);
#pragma unroll
    for (int j = 0; j < 4; ++j)
      bf[j] = *(const f16x8*)(Bs + (wave * 64 + j * 16 + fr) * 32 + fq);
#pragma unroll
    for (int i = 0; i < 4; ++i)
#pragma unroll
      for (int j = 0; j < 4; ++j)
        acc[i][j] = __builtin_amdgcn_mfma_f32_16x16x32_f16(af[i], bf[j], acc[i][j], 0, 0, 0);
    __syncthreads();
  }

  // softmax epilogue, two 32-row halves. Ls stride 261 (coprime with 32).
  int col = lane & 15, rq = (lane >> 4) << 2;
  for (int hf = 0; hf < 2; ++hf) {
    __syncthreads();
#pragma unroll
    for (int j = 0; j < 4; ++j) {
      int v = wave * 64 + j * 16 + col;
      float bias = lb[v];
#pragma unroll
      for (int i = 0; i < 2; ++i) {
        int rloc = i * 16 + rq;
        int ig = hf * 2 + i;
#pragma unroll
        for (int rg = 0; rg < 4; ++rg)
          Ls[(rloc + rg) * 261 + v] = acc[ig][j][rg] + bias;
      }
    }
    __syncthreads();
    if (tid < 128) {
      int r = tid & 31, qd = tid >> 5;
      const float* rowp = Ls + r * 261 + qd * 64;
      float pm = -1e30f;
#pragma unroll 8
      for (int c = 0; c < 64; ++c) pm = fmaxf(pm, rowp[c]);
      pmax[qd][r] = pm;
    }
    __syncthreads();
    if (tid < 32)
      mrow[tid] = fmaxf(fmaxf(pmax[0][tid], pmax[1][tid]), fmaxf(pmax[2][tid], pmax[3][tid]));
    __syncthreads();
    if (tid < 128) {
      int r = tid & 31, qd = tid >> 5;
      const float* rowp = Ls + r * 261 + qd * 64;
      float mr = mrow[r], ps = 0.f;
#pragma unroll 8
      for (int c = 0; c < 64; ++c) ps += __expf(rowp[c] - mr);
      psum[qd][r] = ps;
    }
    __syncthreads();
    if (tid < 32)
      rinv[tid] = 1.f / (psum[0][tid] + psum[1][tid] + psum[2][tid] + psum[3][tid]);
    __syncthreads();
    float* obase = out + (size_t)(m0 + hf * 32) * 256 + tid;
#pragma unroll 4
    for (int r = 0; r < 32; ++r)
      obase[(size_t)r * 256] = __expf(Ls[r * 261 + tid] - mrow[r]) * rinv[r];
  }
}

extern "C" void kernel_launch(void* const* d_in, const int* in_sizes, int n_in,
                              void* d_out, int out_size, void* d_ws, size_t ws_size,
                              hipStream_t stream) {
  const int*   seq = (const int*)d_in[0];
  const float* tab = (const float*)d_in[1];
  const float* cw  = (const float*)d_in[2];
  const float* cb  = (const float*)d_in[3];
  const float* lw  = (const float*)d_in[4];
  const float* lb  = (const float*)d_in[5];
  float* out = (float*)d_out;
  char* ws = (char*)d_ws;
  // workspace layout (needs ~219.4 MB):
  f16* embp = (f16*)(ws);               //  67,600,384 B  [32*2063][512]
  f16* cout = (f16*)(ws + 67600384);    // 134,217,728 B  [65536][1024]
  f16* wt2  = (f16*)(ws + 201818112);   //  16,777,216 B  [256 jk][1024 h][32 e5]
  f16* lt2  = (f16*)(ws + 218595328);   //     786,432 B  [48][256][32]

  hipLaunchKernelGGL(k_gather, dim3(16504), dim3(256), 0, stream, seq, tab, embp);
  hipLaunchKernelGGL(k_twc,    dim3(1024),  dim3(256), 0, stream, cw, wt2);
  hipLaunchKernelGGL(k_twl,    dim3(1536),  dim3(256), 0, stream, lw, lt2);
  hipLaunchKernelGGL(k_conv,   dim3(2048),  dim3(256), 0, stream, embp, wt2, cb, cout);
  hipLaunchKernelGGL(k_lin,    dim3(1024),  dim3(256), 0, stream, embp, cout, lt2, lb, out);
}

// Round 5
// 1153.960 us; speedup vs baseline: 1.0984x; 1.0537x over previous
//
#include <hip/hip_runtime.h>
#include <stdint.h>
#include <stddef.h>

// CharPredictorMultirateFFN on MI355X (gfx950).
// Pipeline: gather(+pad) -> conv_w transpose -> lin_w transpose -> conv GEMM (fp16 MFMA)
//           -> linear GEMM + fused softmax.
//
// R11: counted-vmcnt fine-phase pipeline for k_conv (m201/T3+T4 done right).
// Corrected model: R6's wall was never LDS BW (reads = 25-50% of port) but the 64
// vmcnt(0)-drain+barrier pairs/block (MFMA busy 1.27e6 of 2.07e6 cyc/CU = 61%).
// R7 failed as the m196 anti-pattern (coarse split, depth-1, 2x barriers); R10 failed
// on unified-file registers (276 -> 1 wave/SIMD). R11: one tap = one phase (256
// phases); B taps in 3 rotating 4 KB LDS buffers, stage(p+2) issued at phase p ->
// loads span 2 phases, never drained to 0 (vmcnt(1)/vmcnt(6), vmcnt(0) only at the
// last phase); A slab dbuf staged at t==13. BM=256 BN=64, 4 waves of 64x64 (acc 64,
// ~130 regs) -> LDS 47 KB, 3 blocks/CU: R6 occupancy + pipelined stages. Raw
// s_barrier (no implicit drain), setprio around MFMA (T5, phase-split now exists).
// Frag addressing/XOR swizzle/epilogue are R5/R6-verified verbatim.

typedef _Float16 f16;
typedef __attribute__((ext_vector_type(8))) _Float16 f16x8;
typedef __attribute__((ext_vector_type(4))) float f32x4;

#define SP 2063  // padded rows per batch item: 15 + 2048

__device__ __forceinline__ void gl2lds16(const void* g, void* l) {
  __builtin_amdgcn_global_load_lds((const __attribute__((address_space(1))) void*)g,
                                   (__attribute__((address_space(3))) void*)l, 16, 0, 0);
}

// ---------------- gather: emb_table[seq] -> f16 padded buffer [32][2063][512] --------
__global__ __launch_bounds__(256) void k_gather(const int* __restrict__ seq,
                                                const float* __restrict__ tab,
                                                f16* __restrict__ embp) {
  int row = blockIdx.x * 4 + (threadIdx.x >> 6);   // 0 .. 66015
  int lane = threadIdx.x & 63;
  int b = row / SP;
  int r = row - b * SP;
  f16* dst = embp + (size_t)row * 512 + lane * 8;
  if (r < 15) {
    f16x8 z = {(f16)0, (f16)0, (f16)0, (f16)0, (f16)0, (f16)0, (f16)0, (f16)0};
    *(f16x8*)dst = z;
  } else {
    int idx = seq[b * 2048 + (r - 15)];
    const float4* src = (const float4*)(tab + (size_t)idx * 512 + lane * 8);
    float4 v0 = src[0], v1 = src[1];
    f16x8 o;
    o[0] = (f16)v0.x; o[1] = (f16)v0.y; o[2] = (f16)v0.z; o[3] = (f16)v0.w;
    o[4] = (f16)v1.x; o[5] = (f16)v1.y; o[6] = (f16)v1.z; o[7] = (f16)v1.w;
    *(f16x8*)dst = o;
  }
}

// ---------------- conv_w [H][E][K] f32 -> wt2 [256 jk][1024 h][32 e5] f16 ------------
// jk = j*16 + k ; e = j*32 + e5. Coalesced read of one h-row into LDS, transpose out.
__global__ __launch_bounds__(256) void k_twc(const float* __restrict__ cw,
                                             f16* __restrict__ wt2) {
  __shared__ f16 tile[8192];          // [e][k] in source order (16 KB)
  int h = blockIdx.x;                 // 1024 blocks
  const float4* src = (const float4*)(cw + (size_t)h * 8192);
#pragma unroll
  for (int i = 0; i < 8; ++i) {
    int o = i * 256 + threadIdx.x;    // float4 index, fully coalesced
    float4 v = src[o];
    f16* d = tile + o * 4;
    d[0] = (f16)v.x; d[1] = (f16)v.y; d[2] = (f16)v.z; d[3] = (f16)v.w;
  }
  __syncthreads();
  // thread t = j*16+k writes 32 halves: wt2[(t*1024 + h)*32 + e5] = tile[(j*32+e5)*16 + k]
  int j = threadIdx.x >> 4, k = threadIdx.x & 15;
  f16* dst = wt2 + ((size_t)threadIdx.x * 1024 + h) * 32;
#pragma unroll
  for (int c8 = 0; c8 < 4; ++c8) {
    f16x8 v;
#pragma unroll
    for (int t = 0; t < 8; ++t) v[t] = tile[((j * 32 + c8 * 8 + t) << 4) | k];
    *(f16x8*)(dst + c8 * 8) = v;
  }
}

// ---------------- lin_w [V][F] f32 -> lt2 [48 fblk][256 v][32] f16 -------------------
__global__ __launch_bounds__(256) void k_twl(const float* __restrict__ lw,
                                             f16* __restrict__ lt2) {
  int o = blockIdx.x * 256 + threadIdx.x;  // 393216 outputs
  int f5 = o & 31;
  int v = (o >> 5) & 255;
  int kb = o >> 13;            // 0..47
  int f = (kb << 5) | f5;
  lt2[o] = (f16)lw[(size_t)v * 1536 + f];
}

// ---------------- conv GEMM: [65536 x 8192] x [8192 x 1024] -> relu -> f16 -----------
// 256x64 block, 4 waves stacked in M (each 64x64, acc 64 regs). 256 phases: phase
// p = (j = p>>4 e-block, t = p&15 tap). Per phase: 16 MFMA/wave; issue B-stage(p+2)
// into rotating buf (p+2)%3; A slab dbuf staged at t==13 for j+1. Counted vmcnt,
// raw s_barrier -- no full drain in the steady loop.
__global__ __launch_bounds__(256, 3) void k_conv(const f16* __restrict__ embp,
                                                 const f16* __restrict__ wt2,
                                                 const float* __restrict__ cb,
                                                 f16* __restrict__ cout) {
  __shared__ __align__(16) f16 Asl[2 * 272 * 32];  // 34.8 KB A slab dbuf (rows 0..270 read)
  __shared__ __align__(16) f16 Bb[3 * 64 * 32];    // 12 KB: 3 rotating B tap buffers
  // XCD-pinned swizzle: bid&7 -> XCD, mb spread across XCDs (R3/R5-verified family).
  int bid = blockIdx.x;                // 4096 blocks
  int x8 = bid & 7;
  int s = bid >> 3;                    // 0..511
  int nb = s & 15;                     // 16 N-blocks of 64
  int mb = ((s >> 4) << 3) | x8;       // 0..255
  int n0 = nb << 6, m0 = mb << 8;      // M block = 256 rows
  int b = m0 >> 11, t0 = m0 & 2047;    // 256 | 2048 -> no item straddle
  int tid = threadIdx.x, lane = tid & 63, wave = tid >> 6;   // wave = M strip 0..3
  int fr = lane & 15, q = lane >> 4;
  int prl = tid >> 2, pc = tid & 3;    // staging: row 0..63 within op, phys chunk

  // A main sources (4 ops cover rows 0..255: op c -> rows c*64 + prl).
  // Source fetches logical chunk pc ^ ((row>>1)&3)  (XOR swizzle; LDS dst linear).
  const f16* gAm[4];
#pragma unroll
  for (int c = 0; c < 4; ++c) {
    int pr = c * 64 + prl;
    int clog = pc ^ ((pr >> 1) & 3);
    gAm[c] = embp + (size_t)(b * SP + t0 + pr) * 512 + clog * 8;
  }
  // A tail rows 256..271: each wave stages the same 1 KB (benign same-data WAW;
  // keeps per-thread vmcnt uniform). Row 271 staged but never read.
  const f16* gAt;
  {
    int pr = 256 + (lane >> 2);
    int clog = (lane & 3) ^ ((pr >> 1) & 3);
    gAt = embp + (size_t)(b * SP + t0 + pr) * 512 + clog * 8;
  }
  // B source (1 op: rows 0..63 = h cols n0..n0+63), same swizzle.
  const f16* gBm;
  {
    int clog = pc ^ ((prl >> 1) & 3);
    gBm = wt2 + (size_t)(n0 + prl) * 32 + clog * 8;
  }

  int fqB = (q ^ ((fr >> 1) & 3)) << 3;  // B frag phys chunk (rows % 16 aligned)

  f32x4 zero = {0.f, 0.f, 0.f, 0.f};
  f32x4 acc[4][4];
#pragma unroll
  for (int i = 0; i < 4; ++i)
#pragma unroll
    for (int jj = 0; jj < 4; ++jj) acc[i][jj] = zero;

  f16* aDst0 = Asl + wave * 512;   // + abuf + c*2048 per op
  f16* aTail = Asl + 8192;         // + abuf
  f16* bDst  = Bb + wave * 512;    // + bs*2048

  // prologue: A(0) [5 ops], B(0)->buf0, B(1)->buf1 [2 ops]
#pragma unroll
  for (int c = 0; c < 4; ++c) gl2lds16(gAm[c], aDst0 + c * 2048);
  gl2lds16(gAt, aTail);
  gl2lds16(gBm, bDst);
  gl2lds16(gBm + 32768, bDst + 2048);

  int bs = 0;  // = p % 3
#pragma unroll 1
  for (int p = 0; p < 256; ++p) {
    int t = p & 15, j = p >> 4;
    // Wait: own share of stage(p) (and A slab when due) landed. In-order vmcnt:
    // normal: in-flight B(p)@p-2(1), B(p+1)@p-1(1) -> vmcnt(1) retires B(p).
    // t==14 (A issued at t13, j<15): after B(p)@t12: B(p+1)(1)+A(5)=6 -> vmcnt(6).
    // t==15: vmcnt(1) also forces A retired (issued 2 phases back).
    // p==255: final drain.
    if (p == 255)               asm volatile("s_waitcnt vmcnt(0)" ::: "memory");
    else if (t == 14 && j < 15) asm volatile("s_waitcnt vmcnt(6)" ::: "memory");
    else                        asm volatile("s_waitcnt vmcnt(1)" ::: "memory");
    __builtin_amdgcn_s_barrier();   // raw barrier: everyone's stage(p) is in LDS;
                                    // phase p-1 reads completed (consumed by MFMA).
    // issue stage(p+2) into buf (p+2)%3 (the buffer last read at phase p-1)
    if (p < 254) {
      int bs2 = bs + 2; if (bs2 >= 3) bs2 -= 3;
      gl2lds16(gBm + (size_t)(p + 2) * 32768, bDst + bs2 * 2048);
    }
    // A slab for j+1 (first read at phase (j+1)*16, 3 phases away)
    if (t == 13 && j < 15) {
      int abn = ((j + 1) & 1) * 8704;
#pragma unroll
      for (int c = 0; c < 4; ++c)
        gl2lds16(gAm[c] + (j + 1) * 32, aDst0 + abn + c * 2048);
      gl2lds16(gAt + (j + 1) * 32, aTail + abn);
    }
    // compute tap t of e-block j from Asl[j&1], Bb[bs]
    const f16* Ab = Asl + (j & 1) * 8704;
    const f16* Bc = Bb + bs * 2048;
    f16x8 bf[4];
#pragma unroll
    for (int jj = 0; jj < 4; ++jj)
      bf[jj] = *(const f16x8*)(Bc + (jj * 16 + fr) * 32 + fqB);
    // A frag: slab row = t + wave*64 + i*16 + fr ; swizzle incl. tap offset t.
    int aswz = ((t + fr) >> 1) & 3;
    const f16* ap = Ab + (size_t)(t + wave * 64 + fr) * 32 + ((q ^ aswz) << 3);
    __builtin_amdgcn_s_setprio(1);
#pragma unroll
    for (int i = 0; i < 4; ++i) {
      f16x8 af = *(const f16x8*)(ap + i * 512);
#pragma unroll
      for (int jj = 0; jj < 4; ++jj)
        acc[i][jj] = __builtin_amdgcn_mfma_f32_16x16x32_f16(af, bf[jj], acc[i][jj], 0, 0, 0);
    }
    __builtin_amdgcn_s_setprio(0);
    ++bs; if (bs == 3) bs = 0;
  }

  // epilogue: bias + relu + f16 store. C/D: col=lane&15 (n), row=(lane>>4)*4+reg (m)
  int col = lane & 15, rq = (lane >> 4) << 2;
  int mbase = m0 + wave * 64 + rq;
  int nbase = n0 + col;
#pragma unroll
  for (int jj = 0; jj < 4; ++jj) {
    int h = nbase + jj * 16;
    float bias = cb[h];
#pragma unroll
    for (int i = 0; i < 4; ++i) {
      int m = mbase + i * 16;
#pragma unroll
      for (int rg = 0; rg < 4; ++rg) {
        float v = acc[i][jj][rg] + bias;
        v = v > 0.f ? v : 0.f;
        cout[(size_t)(m + rg) * 1024 + h] = (f16)v;
      }
    }
  }
}

// ---------------- linear GEMM [65536 x 1536] x [1536 x 256] + fused softmax ----------
__global__ __launch_bounds__(256) void k_lin(const f16* __restrict__ embp,
                                             const f16* __restrict__ cout,
                                             const f16* __restrict__ lt2,
                                             const float* __restrict__ lb,
                                             float* __restrict__ out) {
  __shared__ __align__(16) char smem[32 * 261 * 4];  // Ls overlays As|Bs
  __shared__ float pmax[4][32], psum[4][32], mrow[32], rinv[32];
  f16* As = (f16*)smem;             // [64][32]   4 KB
  f16* Bs = (f16*)(smem + 4096);    // [256][32] 16 KB
  float* Ls = (float*)smem;         // [32][261] f32 epilogue logits
  int m0 = blockIdx.x << 6;
  int b = m0 >> 11, t0 = m0 & 2047;
  int tid = threadIdx.x, lane = tid & 63, wave = tid >> 6;
  int sr = lane >> 2, sc = (lane & 3) << 3;
  const f16* gAe = embp + (size_t)(b * SP + 15 + t0 + wave * 16 + sr) * 512 + sc;
  const f16* gAc = cout + (size_t)(m0 + wave * 16 + sr) * 1024 + sc;
  f16* lA = As + wave * 512;
  int fr = lane & 15, fq = (lane >> 4) << 3;
  f32x4 zero = {0.f, 0.f, 0.f, 0.f};
  f32x4 acc[4][4];
#pragma unroll
  for (int i = 0; i < 4; ++i)
#pragma unroll
    for (int j = 0; j < 4; ++j) acc[i][j] = zero;

  for (int kb = 0; kb < 48; ++kb) {
    if (kb < 16) gl2lds16(gAe + kb * 32, lA);
    else         gl2lds16(gAc + (kb - 16) * 32, lA);
#pragma unroll
    for (int jj = 0; jj < 4; ++jj) {
      int c = wave * 4 + jj;
      gl2lds16(lt2 + (size_t)kb * 8192 + (c * 16 + sr) * 32 + sc, Bs + c * 512);
    }
    __syncthreads();
    f16x8 af[4], bf[4];
#pragma unroll
    for (int i = 0; i < 4; ++i)
      af[i] = *(const f16x8*)(As + (i * 16 + fr) * 32 + fq);
#pragma unroll
    for (int j = 0; j < 4; ++j)
      bf[j] = *(const f16x8*)(Bs + (wave * 64 + j * 16 + fr) * 32 + fq);
#pragma unroll
    for (int i = 0; i < 4; ++i)
#pragma unroll
      for (int j = 0; j < 4; ++j)
        acc[i][j] = __builtin_amdgcn_mfma_f32_16x16x32_f16(af[i], bf[j], acc[i][j], 0, 0, 0);
    __syncthreads();
  }

  // softmax epilogue, two 32-row halves. Ls stride 261 (coprime with 32).
  int col = lane & 15, rq = (lane >> 4) << 2;
  for (int hf = 0; hf < 2; ++hf) {
    __syncthreads();
#pragma unroll
    for (int j = 0; j < 4; ++j) {
      int v = wave * 64 + j * 16 + col;
      float bias = lb[v];
#pragma unroll
      for (int i = 0; i < 2; ++i) {
        int rloc = i * 16 + rq;
        int ig = hf * 2 + i;
#pragma unroll
        for (int rg = 0; rg < 4; ++rg)
          Ls[(rloc + rg) * 261 + v] = acc[ig][j][rg] + bias;
      }
    }
    __syncthreads();
    if (tid < 128) {
      int r = tid & 31, qd = tid >> 5;
      const float* rowp = Ls + r * 261 + qd * 64;
      float pm = -1e30f;
#pragma unroll 8
      for (int c = 0; c < 64; ++c) pm = fmaxf(pm, rowp[c]);
      pmax[qd][r] = pm;
    }
    __syncthreads();
    if (tid < 32)
      mrow[tid] = fmaxf(fmaxf(pmax[0][tid], pmax[1][tid]), fmaxf(pmax[2][tid], pmax[3][tid]));
    __syncthreads();
    if (tid < 128) {
      int r = tid & 31, qd = tid >> 5;
      const float* rowp = Ls + r * 261 + qd * 64;
      float mr = mrow[r], ps = 0.f;
#pragma unroll 8
      for (int c = 0; c < 64; ++c) ps += __expf(rowp[c] - mr);
      psum[qd][r] = ps;
    }
    __syncthreads();
    if (tid < 32)
      rinv[tid] = 1.f / (psum[0][tid] + psum[1][tid] + psum[2][tid] + psum[3][tid]);
    __syncthreads();
    float* obase = out + (size_t)(m0 + hf * 32) * 256 + tid;
#pragma unroll 4
    for (int r = 0; r < 32; ++r)
      obase[(size_t)r * 256] = __expf(Ls[r * 261 + tid] - mrow[r]) * rinv[r];
  }
}

extern "C" void kernel_launch(void* const* d_in, const int* in_sizes, int n_in,
                              void* d_out, int out_size, void* d_ws, size_t ws_size,
                              hipStream_t stream) {
  const int*   seq = (const int*)d_in[0];
  const float* tab = (const float*)d_in[1];
  const float* cw  = (const float*)d_in[2];
  const float* cb  = (const float*)d_in[3];
  const float* lw  = (const float*)d_in[4];
  const float* lb  = (const float*)d_in[5];
  float* out = (float*)d_out;
  char* ws = (char*)d_ws;
  // workspace layout (needs ~219.4 MB):
  f16* embp = (f16*)(ws);               //  67,600,384 B  [32*2063][512]
  f16* cout = (f16*)(ws + 67600384);    // 134,217,728 B  [65536][1024]
  f16* wt2  = (f16*)(ws + 201818112);   //  16,777,216 B  [256 jk][1024 h][32 e5]
  f16* lt2  = (f16*)(ws + 218595328);   //     786,432 B  [48][256][32]

  hipLaunchKernelGGL(k_gather, dim3(16504), dim3(256), 0, stream, seq, tab, embp);
  hipLaunchKernelGGL(k_twc,    dim3(1024),  dim3(256), 0, stream, cw, wt2);
  hipLaunchKernelGGL(k_twl,    dim3(1536),  dim3(256), 0, stream, lw, lt2);
  hipLaunchKernelGGL(k_conv,   dim3(4096),  dim3(256), 0, stream, embp, wt2, cb, cout);
  hipLaunchKernelGGL(k_lin,    dim3(1024),  dim3(256), 0, stream, embp, cout, lt2, lb, out);
}

// Round 6
// 1033.833 us; speedup vs baseline: 1.2261x; 1.1162x over previous
//
#include <hip/hip_runtime.h>
#include <stdint.h>
#include <stddef.h>

// CharPredictorMultirateFFN on MI355X (gfx950).
// Pipeline: gather(+pad) -> conv_w transpose -> lin_w transpose -> conv GEMM (fp16 MFMA)
//           -> linear GEMM + fused softmax.
//
// R12: minimal 2-phase pipeline (T3 recipe, verbatim) for k_conv. Evidence across
// R6/R7/R11: barrier count dominates (128/256/256 barriers -> 68/63/49 MfmaUtil);
// phase granularity below 4 taps is poison; R6's residual 274 us stall is the
// zero-overlap B stage (issued then immediately drained, full L2 latency x64).
// R12 keeps R6's 4-tap granularity and R11's verified BM=256/BN=64 addressing, with
// ONE __syncthreads per group and B staged one group AHEAD into a 2x16 KB double
// buffer -> the barrier's vmcnt(0) waits on loads issued a full group (~310+ cyc)
// earlier. A slab single-buffered (17.4 KB), restaged per j behind an extra barrier
// pair (16x, L2-warm via mb-XCD pinning). LDS 50176 B -> 3 blocks/CU. No inline asm.

typedef _Float16 f16;
typedef __attribute__((ext_vector_type(8))) _Float16 f16x8;
typedef __attribute__((ext_vector_type(4))) float f32x4;

#define SP 2063  // padded rows per batch item: 15 + 2048

__device__ __forceinline__ void gl2lds16(const void* g, void* l) {
  __builtin_amdgcn_global_load_lds((const __attribute__((address_space(1))) void*)g,
                                   (__attribute__((address_space(3))) void*)l, 16, 0, 0);
}

// ---------------- gather: emb_table[seq] -> f16 padded buffer [32][2063][512] --------
__global__ __launch_bounds__(256) void k_gather(const int* __restrict__ seq,
                                                const float* __restrict__ tab,
                                                f16* __restrict__ embp) {
  int row = blockIdx.x * 4 + (threadIdx.x >> 6);   // 0 .. 66015
  int lane = threadIdx.x & 63;
  int b = row / SP;
  int r = row - b * SP;
  f16* dst = embp + (size_t)row * 512 + lane * 8;
  if (r < 15) {
    f16x8 z = {(f16)0, (f16)0, (f16)0, (f16)0, (f16)0, (f16)0, (f16)0, (f16)0};
    *(f16x8*)dst = z;
  } else {
    int idx = seq[b * 2048 + (r - 15)];
    const float4* src = (const float4*)(tab + (size_t)idx * 512 + lane * 8);
    float4 v0 = src[0], v1 = src[1];
    f16x8 o;
    o[0] = (f16)v0.x; o[1] = (f16)v0.y; o[2] = (f16)v0.z; o[3] = (f16)v0.w;
    o[4] = (f16)v1.x; o[5] = (f16)v1.y; o[6] = (f16)v1.z; o[7] = (f16)v1.w;
    *(f16x8*)dst = o;
  }
}

// ---------------- conv_w [H][E][K] f32 -> wt2 [256 jk][1024 h][32 e5] f16 ------------
// jk = j*16 + k ; e = j*32 + e5. Coalesced read of one h-row into LDS, transpose out.
__global__ __launch_bounds__(256) void k_twc(const float* __restrict__ cw,
                                             f16* __restrict__ wt2) {
  __shared__ f16 tile[8192];          // [e][k] in source order (16 KB)
  int h = blockIdx.x;                 // 1024 blocks
  const float4* src = (const float4*)(cw + (size_t)h * 8192);
#pragma unroll
  for (int i = 0; i < 8; ++i) {
    int o = i * 256 + threadIdx.x;    // float4 index, fully coalesced
    float4 v = src[o];
    f16* d = tile + o * 4;
    d[0] = (f16)v.x; d[1] = (f16)v.y; d[2] = (f16)v.z; d[3] = (f16)v.w;
  }
  __syncthreads();
  // thread t = j*16+k writes 32 halves: wt2[(t*1024 + h)*32 + e5] = tile[(j*32+e5)*16 + k]
  int j = threadIdx.x >> 4, k = threadIdx.x & 15;
  f16* dst = wt2 + ((size_t)threadIdx.x * 1024 + h) * 32;
#pragma unroll
  for (int c8 = 0; c8 < 4; ++c8) {
    f16x8 v;
#pragma unroll
    for (int t = 0; t < 8; ++t) v[t] = tile[((j * 32 + c8 * 8 + t) << 4) | k];
    *(f16x8*)(dst + c8 * 8) = v;
  }
}

// ---------------- lin_w [V][F] f32 -> lt2 [48 fblk][256 v][32] f16 -------------------
__global__ __launch_bounds__(256) void k_twl(const float* __restrict__ lw,
                                             f16* __restrict__ lt2) {
  int o = blockIdx.x * 256 + threadIdx.x;  // 393216 outputs
  int f5 = o & 31;
  int v = (o >> 5) & 255;
  int kb = o >> 13;            // 0..47
  int f = (kb << 5) | f5;
  lt2[o] = (f16)lw[(size_t)v * 1536 + f];
}

// ---------------- conv GEMM: [65536 x 8192] x [8192 x 1024] -> relu -> f16 -----------
// 256x64 block, 4 waves stacked in M (each 64x64, acc 64 regs, R11-verified
// addressing). 64 groups of 4 taps. Per group: issue B(g+1) into buf (g+1)&1 ->
// compute 64 MFMA from buf g&1 -> __syncthreads (vmcnt(0) covered by one full group).
// A slab (272 rows, 17.4 KB) single-buffered, restaged per j behind a barrier pair.
__global__ __launch_bounds__(256, 3) void k_conv(const f16* __restrict__ embp,
                                                 const f16* __restrict__ wt2,
                                                 const float* __restrict__ cb,
                                                 f16* __restrict__ cout) {
  __shared__ __align__(16) f16 Asl[272 * 32];        // 17.4 KB A slab (rows 0..270 read)
  __shared__ __align__(16) f16 Bb[2 * 4 * 64 * 32];  // 32 KB: dbuf x 4 taps x 64 rows
  // mb-XCD-pinned swizzle (R6-family): bid&7 -> XCD; A slab L2-shared by the 16
  // nb-blocks of the same mb on that XCD.
  int bid = blockIdx.x;                // 4096 blocks
  int x8 = bid & 7;
  int s = bid >> 3;                    // 0..511
  int nb = s & 15;                     // 16 N-blocks of 64
  int mb = ((s >> 4) << 3) | x8;       // 0..255
  int n0 = nb << 6, m0 = mb << 8;      // M block = 256 rows
  int b = m0 >> 11, t0 = m0 & 2047;    // 256 | 2048 -> no item straddle
  int tid = threadIdx.x, lane = tid & 63, wave = tid >> 6;   // wave = M strip 0..3
  int fr = lane & 15, q = lane >> 4;
  int prl = tid >> 2, pc = tid & 3;    // staging: row 0..63 within op, phys chunk

  // A main sources (4 ops cover rows 0..255: op c -> rows c*64 + prl).
  // Source fetches logical chunk pc ^ ((row>>1)&3)  (XOR swizzle; LDS dst linear).
  const f16* gAm[4];
#pragma unroll
  for (int c = 0; c < 4; ++c) {
    int pr = c * 64 + prl;
    int clog = pc ^ ((pr >> 1) & 3);
    gAm[c] = embp + (size_t)(b * SP + t0 + pr) * 512 + clog * 8;
  }
  // A tail rows 256..271: each wave stages the same 1 KB (benign same-data WAW).
  const f16* gAt;
  {
    int pr = 256 + (lane >> 2);
    int clog = (lane & 3) ^ ((pr >> 1) & 3);
    gAt = embp + (size_t)(b * SP + t0 + pr) * 512 + clog * 8;
  }
  // B source (1 op per tap: rows 0..63 = h cols n0..n0+63), same swizzle.
  const f16* gBm;
  {
    int clog = pc ^ ((prl >> 1) & 3);
    gBm = wt2 + (size_t)(n0 + prl) * 32 + clog * 8;
  }

  int fqB = (q ^ ((fr >> 1) & 3)) << 3;  // B frag phys chunk (rows % 16 aligned)

  f32x4 zero = {0.f, 0.f, 0.f, 0.f};
  f32x4 acc[4][4];
#pragma unroll
  for (int i = 0; i < 4; ++i)
#pragma unroll
    for (int jj = 0; jj < 4; ++jj) acc[i][jj] = zero;

  f16* aD0 = Asl + wave * 512;         // + c*2048 per op
  f16* bD0 = Bb + wave * 512;          // + d*8192 + t*2048

  // prologue: A(j=0) [5 ops], B(group 0) -> buf 0 [4 ops]
#pragma unroll
  for (int c = 0; c < 4; ++c) gl2lds16(gAm[c], aD0 + c * 2048);
  gl2lds16(gAt, Asl + 8192);
#pragma unroll
  for (int t = 0; t < 4; ++t) gl2lds16(gBm + (size_t)t * 32768, bD0 + t * 2048);
  __syncthreads();

#pragma unroll 1
  for (int g = 0; g < 64; ++g) {
    int j = g >> 2;
    // stage NEXT group's 4 B taps into buf (g+1)&1 (read last at group g-1;
    // all waves passed the end-of-(g-1) barrier -> write-safe)
    if (g < 63) {
      const f16* src = gBm + (size_t)(g + 1) * 4 * 32768;
      f16* dst = bD0 + ((g + 1) & 1) * 8192;
#pragma unroll
      for (int t = 0; t < 4; ++t) gl2lds16(src + (size_t)t * 32768, dst + t * 2048);
    }
    // compute group g: taps k = (g&3)*4 .. +3, from Asl and Bb[g&1]
    const f16* Bc = Bb + (g & 1) * 8192;
#pragma unroll
    for (int t = 0; t < 4; ++t) {
      int k = ((g & 3) << 2) + t;
      // A frag: slab row = k + wave*64 + i*16 + fr ; swizzle incl. tap offset k.
      int aswz = ((k + fr) >> 1) & 3;
      const f16* ap = Asl + (size_t)(k + wave * 64 + fr) * 32 + ((q ^ aswz) << 3);
      f16x8 bf[4];
#pragma unroll
      for (int jj = 0; jj < 4; ++jj)
        bf[jj] = *(const f16x8*)(Bc + t * 2048 + (jj * 16 + fr) * 32 + fqB);
#pragma unroll
      for (int i = 0; i < 4; ++i) {
        f16x8 af = *(const f16x8*)(ap + i * 512);
#pragma unroll
        for (int jj = 0; jj < 4; ++jj)
          acc[i][jj] = __builtin_amdgcn_mfma_f32_16x16x32_f16(af, bf[jj], acc[i][jj], 0, 0, 0);
      }
    }
    __syncthreads();   // vmcnt(0): B(g+1) landed (issued one full group ago);
                       // all waves done reading Asl/Bb[g&1].
    // j boundary: restage A for j+1 (A is single-buffered; waves just finished
    // the last taps of j and passed the barrier above)
    if ((g & 3) == 3 && j < 15) {
#pragma unroll
      for (int c = 0; c < 4; ++c) gl2lds16(gAm[c] + (j + 1) * 32, aD0 + c * 2048);
      gl2lds16(gAt + (j + 1) * 32, Asl + 8192);
      __syncthreads();  // drain A(j+1) (L2-warm via mb pinning) before its first read
    }
  }

  // epilogue: bias + relu + f16 store. C/D: col=lane&15 (n), row=(lane>>4)*4+reg (m)
  int col = lane & 15, rq = (lane >> 4) << 2;
  int mbase = m0 + wave * 64 + rq;
  int nbase = n0 + col;
#pragma unroll
  for (int jj = 0; jj < 4; ++jj) {
    int h = nbase + jj * 16;
    float bias = cb[h];
#pragma unroll
    for (int i = 0; i < 4; ++i) {
      int m = mbase + i * 16;
#pragma unroll
      for (int rg = 0; rg < 4; ++rg) {
        float v = acc[i][jj][rg] + bias;
        v = v > 0.f ? v : 0.f;
        cout[(size_t)(m + rg) * 1024 + h] = (f16)v;
      }
    }
  }
}

// ---------------- linear GEMM [65536 x 1536] x [1536 x 256] + fused softmax ----------
__global__ __launch_bounds__(256) void k_lin(const f16* __restrict__ embp,
                                             const f16* __restrict__ cout,
                                             const f16* __restrict__ lt2,
                                             const float* __restrict__ lb,
                                             float* __restrict__ out) {
  __shared__ __align__(16) char smem[32 * 261 * 4];  // Ls overlays As|Bs
  __shared__ float pmax[4][32], psum[4][32], mrow[32], rinv[32];
  f16* As = (f16*)smem;             // [64][32]   4 KB
  f16* Bs = (f16*)(smem + 4096);    // [256][32] 16 KB
  float* Ls = (float*)smem;         // [32][261] f32 epilogue logits
  int m0 = blockIdx.x << 6;
  int b = m0 >> 11, t0 = m0 & 2047;
  int tid = threadIdx.x, lane = tid & 63, wave = tid >> 6;
  int sr = lane >> 2, sc = (lane & 3) << 3;
  const f16* gAe = embp + (size_t)(b * SP + 15 + t0 + wave * 16 + sr) * 512 + sc;
  const f16* gAc = cout + (size_t)(m0 + wave * 16 + sr) * 1024 + sc;
  f16* lA = As + wave * 512;
  int fr = lane & 15, fq = (lane >> 4) << 3;
  f32x4 zero = {0.f, 0.f, 0.f, 0.f};
  f32x4 acc[4][4];
#pragma unroll
  for (int i = 0; i < 4; ++i)
#pragma unroll
    for (int j = 0; j < 4; ++j) acc[i][j] = zero;

  for (int kb = 0; kb < 48; ++kb) {
    if (kb < 16) gl2lds16(gAe + kb * 32, lA);
    else         gl2lds16(gAc + (kb - 16) * 32, lA);
#pragma unroll
    for (int jj = 0; jj < 4; ++jj) {
      int c = wave * 4 + jj;
      gl2lds16(lt2 + (size_t)kb * 8192 + (c * 16 + sr) * 32 + sc, Bs + c * 512);
    }
    __syncthreads();
    f16x8 af[4], bf[4];
#pragma unroll
    for (int i = 0; i < 4; ++i)
      af[i] = *(const f16x8*)(As + (i * 16 + fr) * 32 + fq);
#pragma unroll
    for (int j = 0; j < 4; ++j)
      bf[j] = *(const f16x8*)(Bs + (wave * 64 + j * 16 + fr) * 32 + fq);
#pragma unroll
    for (int i = 0; i < 4; ++i)
#pragma unroll
      for (int j = 0; j < 4; ++j)
        acc[i][j] = __builtin_amdgcn_mfma_f32_16x16x32_f16(af[i], bf[j], acc[i][j], 0, 0, 0);
    __syncthreads();
  }

  // softmax epilogue, two 32-row halves. Ls stride 261 (coprime with 32).
  int col = lane & 15, rq = (lane >> 4) << 2;
  for (int hf = 0; hf < 2; ++hf) {
    __syncthreads();
#pragma unroll
    for (int j = 0; j < 4; ++j) {
      int v = wave * 64 + j * 16 + col;
      float bias = lb[v];
#pragma unroll
      for (int i = 0; i < 2; ++i) {
        int rloc = i * 16 + rq;
        int ig = hf * 2 + i;
#pragma unroll
        for (int rg = 0; rg < 4; ++rg)
          Ls[(rloc + rg) * 261 + v] = acc[ig][j][rg] + bias;
      }
    }
    __syncthreads();
    if (tid < 128) {
      int r = tid & 31, qd = tid >> 5;
      const float* rowp = Ls + r * 261 + qd * 64;
      float pm = -1e30f;
#pragma unroll 8
      for (int c = 0; c < 64; ++c) pm = fmaxf(pm, rowp[c]);
      pmax[qd][r] = pm;
    }
    __syncthreads();
    if (tid < 32)
      mrow[tid] = fmaxf(fmaxf(pmax[0][tid], pmax[1][tid]), fmaxf(pmax[2][tid], pmax[3][tid]));
    __syncthreads();
    if (tid < 128) {
      int r = tid & 31, qd = tid >> 5;
      const float* rowp = Ls + r * 261 + qd * 64;
      float mr = mrow[r], ps = 0.f;
#pragma unroll 8
      for (int c = 0; c < 64; ++c) ps += __expf(rowp[c] - mr);
      psum[qd][r] = ps;
    }
    __syncthreads();
    if (tid < 32)
      rinv[tid] = 1.f / (psum[0][tid] + psum[1][tid] + psum[2][tid] + psum[3][tid]);
    __syncthreads();
    float* obase = out + (size_t)(m0 + hf * 32) * 256 + tid;
#pragma unroll 4
    for (int r = 0; r < 32; ++r)
      obase[(size_t)r * 256] = __expf(Ls[r * 261 + tid] - mrow[r]) * rinv[r];
  }
}

extern "C" void kernel_launch(void* const* d_in, const int* in_sizes, int n_in,
                              void* d_out, int out_size, void* d_ws, size_t ws_size,
                              hipStream_t stream) {
  const int*   seq = (const int*)d_in[0];
  const float* tab = (const float*)d_in[1];
  const float* cw  = (const float*)d_in[2];
  const float* cb  = (const float*)d_in[3];
  const float* lw  = (const float*)d_in[4];
  const float* lb  = (const float*)d_in[5];
  float* out = (float*)d_out;
  char* ws = (char*)d_ws;
  // workspace layout (needs ~219.4 MB):
  f16* embp = (f16*)(ws);               //  67,600,384 B  [32*2063][512]
  f16* cout = (f16*)(ws + 67600384);    // 134,217,728 B  [65536][1024]
  f16* wt2  = (f16*)(ws + 201818112);   //  16,777,216 B  [256 jk][1024 h][32 e5]
  f16* lt2  = (f16*)(ws + 218595328);   //     786,432 B  [48][256][32]

  hipLaunchKernelGGL(k_gather, dim3(16504), dim3(256), 0, stream, seq, tab, embp);
  hipLaunchKernelGGL(k_twc,    dim3(1024),  dim3(256), 0, stream, cw, wt2);
  hipLaunchKernelGGL(k_twl,    dim3(1536),  dim3(256), 0, stream, lw, lt2);
  hipLaunchKernelGGL(k_conv,   dim3(4096),  dim3(256), 0, stream, embp, wt2, cb, cout);
  hipLaunchKernelGGL(k_lin,    dim3(1024),  dim3(256), 0, stream, embp, cout, lt2, lb, out);
}

// Round 7
// 975.019 us; speedup vs baseline: 1.3000x; 1.0603x over previous
//
#include <hip/hip_runtime.h>
#include <stdint.h>
#include <stddef.h>

// CharPredictorMultirateFFN on MI355X (gfx950).
// Pipeline: gather(+pad) -> conv_w transpose -> lin_w transpose -> conv GEMM (fp16 MFMA)
//           -> linear GEMM + fused softmax.
//
// R13: bigger wave tile to break the LDS-read wall. R6 and R12 (different schedules)
// both converge at MfmaUtil ~68 and 79-84 B/cyc/CU of ds_read_b128 traffic (= the 85
// B/cyc m134 ceiling): per-CU demand is LDS 1.57e6 cyc > MFMA 1.27e6 cyc. FLOP per
// LDS-byte = WM*WN/(WM+WN): 64x64 -> 32, 128x64 -> 42.7 (LDS x0.75 -> 1.18e6 < MFMA).
// R13 keeps the R12 schedule verbatim (2-phase B dbuf, one syncthreads per 4-tap
// group, A restaged per j behind a barrier pair) and changes only geometry:
// block 512x64, 4 waves stacked in M, each 128x64 (acc[8][4]=128 AGPR + ~80 VGPR
// <= 256 -> 2 waves/SIMD via __launch_bounds__(256,2); R10's 276-reg failure came
// from its fatter loop body). LDS 66.5 KB -> 2 blocks/CU. Grid 2048, mb-XCD swizzle.

typedef _Float16 f16;
typedef __attribute__((ext_vector_type(8))) _Float16 f16x8;
typedef __attribute__((ext_vector_type(4))) float f32x4;

#define SP 2063  // padded rows per batch item: 15 + 2048

__device__ __forceinline__ void gl2lds16(const void* g, void* l) {
  __builtin_amdgcn_global_load_lds((const __attribute__((address_space(1))) void*)g,
                                   (__attribute__((address_space(3))) void*)l, 16, 0, 0);
}

// ---------------- gather: emb_table[seq] -> f16 padded buffer [32][2063][512] --------
__global__ __launch_bounds__(256) void k_gather(const int* __restrict__ seq,
                                                const float* __restrict__ tab,
                                                f16* __restrict__ embp) {
  int row = blockIdx.x * 4 + (threadIdx.x >> 6);   // 0 .. 66015
  int lane = threadIdx.x & 63;
  int b = row / SP;
  int r = row - b * SP;
  f16* dst = embp + (size_t)row * 512 + lane * 8;
  if (r < 15) {
    f16x8 z = {(f16)0, (f16)0, (f16)0, (f16)0, (f16)0, (f16)0, (f16)0, (f16)0};
    *(f16x8*)dst = z;
  } else {
    int idx = seq[b * 2048 + (r - 15)];
    const float4* src = (const float4*)(tab + (size_t)idx * 512 + lane * 8);
    float4 v0 = src[0], v1 = src[1];
    f16x8 o;
    o[0] = (f16)v0.x; o[1] = (f16)v0.y; o[2] = (f16)v0.z; o[3] = (f16)v0.w;
    o[4] = (f16)v1.x; o[5] = (f16)v1.y; o[6] = (f16)v1.z; o[7] = (f16)v1.w;
    *(f16x8*)dst = o;
  }
}

// ---------------- conv_w [H][E][K] f32 -> wt2 [256 jk][1024 h][32 e5] f16 ------------
// jk = j*16 + k ; e = j*32 + e5. Coalesced read of one h-row into LDS, transpose out.
__global__ __launch_bounds__(256) void k_twc(const float* __restrict__ cw,
                                             f16* __restrict__ wt2) {
  __shared__ f16 tile[8192];          // [e][k] in source order (16 KB)
  int h = blockIdx.x;                 // 1024 blocks
  const float4* src = (const float4*)(cw + (size_t)h * 8192);
#pragma unroll
  for (int i = 0; i < 8; ++i) {
    int o = i * 256 + threadIdx.x;    // float4 index, fully coalesced
    float4 v = src[o];
    f16* d = tile + o * 4;
    d[0] = (f16)v.x; d[1] = (f16)v.y; d[2] = (f16)v.z; d[3] = (f16)v.w;
  }
  __syncthreads();
  // thread t = j*16+k writes 32 halves: wt2[(t*1024 + h)*32 + e5] = tile[(j*32+e5)*16 + k]
  int j = threadIdx.x >> 4, k = threadIdx.x & 15;
  f16* dst = wt2 + ((size_t)threadIdx.x * 1024 + h) * 32;
#pragma unroll
  for (int c8 = 0; c8 < 4; ++c8) {
    f16x8 v;
#pragma unroll
    for (int t = 0; t < 8; ++t) v[t] = tile[((j * 32 + c8 * 8 + t) << 4) | k];
    *(f16x8*)(dst + c8 * 8) = v;
  }
}

// ---------------- lin_w [V][F] f32 -> lt2 [48 fblk][256 v][32] f16 -------------------
__global__ __launch_bounds__(256) void k_twl(const float* __restrict__ lw,
                                             f16* __restrict__ lt2) {
  int o = blockIdx.x * 256 + threadIdx.x;  // 393216 outputs
  int f5 = o & 31;
  int v = (o >> 5) & 255;
  int kb = o >> 13;            // 0..47
  int f = (kb << 5) | f5;
  lt2[o] = (f16)lw[(size_t)v * 1536 + f];
}

// ---------------- conv GEMM: [65536 x 8192] x [8192 x 1024] -> relu -> f16 -----------
// 512x64 block, 4 waves stacked in M (each 128x64: acc[8][4], 128 AGPR). 64 groups
// of 4 taps, R12 schedule: issue B(g+1) into buf (g+1)&1 -> compute 128 MFMA/wave ->
// __syncthreads (vmcnt(0) covered by one full group). A slab (528 rows, 33 KB)
// single-buffered, restaged per j behind a barrier pair. LDS 66.5 KB, 2 blocks/CU.
__global__ __launch_bounds__(256, 2) void k_conv(const f16* __restrict__ embp,
                                                 const f16* __restrict__ wt2,
                                                 const float* __restrict__ cb,
                                                 f16* __restrict__ cout) {
  __shared__ __align__(16) f16 Asl[528 * 32];        // 33 KB A slab (rows 0..526 read)
  __shared__ __align__(16) f16 Bb[2 * 4 * 64 * 32];  // 32 KB: dbuf x 4 taps x 64 rows
  // mb-XCD-pinned swizzle (R6/R12-family): bid&7 -> XCD; A slab L2-shared by the 16
  // nb-blocks of the same mb on that XCD.
  int bid = blockIdx.x;                // 2048 blocks
  int x8 = bid & 7;
  int s = bid >> 3;                    // 0..255
  int nb = s & 15;                     // 16 N-blocks of 64
  int mb = ((s >> 4) << 3) | x8;       // 0..127
  int n0 = nb << 6, m0 = mb << 9;      // M block = 512 rows
  int b = m0 >> 11, t0 = m0 & 2047;    // 512 | 2048 -> no item straddle
  int tid = threadIdx.x, lane = tid & 63, wave = tid >> 6;   // wave = M strip 0..3
  int fr = lane & 15, q = lane >> 4;
  int prl = tid >> 2, pc = tid & 3;    // staging: row 0..63 within op, phys chunk

  // A main sources (8 ops cover rows 0..511: op c -> rows c*64 + prl).
  // Source fetches logical chunk pc ^ ((row>>1)&3)  (XOR swizzle; LDS dst linear).
  const f16* gAm[8];
#pragma unroll
  for (int c = 0; c < 8; ++c) {
    int pr = c * 64 + prl;
    int clog = pc ^ ((pr >> 1) & 3);
    gAm[c] = embp + (size_t)(b * SP + t0 + pr) * 512 + clog * 8;
  }
  // A tail rows 512..527: each wave stages the same 1 KB (benign same-data WAW;
  // row 527 staged but never read).
  const f16* gAt;
  {
    int pr = 512 + (lane >> 2);
    int clog = (lane & 3) ^ ((pr >> 1) & 3);
    gAt = embp + (size_t)(b * SP + t0 + pr) * 512 + clog * 8;
  }
  // B source (1 op per tap: rows 0..63 = h cols n0..n0+63), same swizzle.
  const f16* gBm;
  {
    int clog = pc ^ ((prl >> 1) & 3);
    gBm = wt2 + (size_t)(n0 + prl) * 32 + clog * 8;
  }

  int fqB = (q ^ ((fr >> 1) & 3)) << 3;  // B frag phys chunk (rows % 16 aligned)

  f32x4 zero = {0.f, 0.f, 0.f, 0.f};
  f32x4 acc[8][4];
#pragma unroll
  for (int i = 0; i < 8; ++i)
#pragma unroll
    for (int jj = 0; jj < 4; ++jj) acc[i][jj] = zero;

  f16* aD0 = Asl + wave * 512;         // + c*2048 per op
  f16* bD0 = Bb + wave * 512;          // + d*8192 + t*2048

  // prologue: A(j=0) [9 ops], B(group 0) -> buf 0 [4 ops]
#pragma unroll
  for (int c = 0; c < 8; ++c) gl2lds16(gAm[c], aD0 + c * 2048);
  gl2lds16(gAt, Asl + 16384);
#pragma unroll
  for (int t = 0; t < 4; ++t) gl2lds16(gBm + (size_t)t * 32768, bD0 + t * 2048);
  __syncthreads();

#pragma unroll 1
  for (int g = 0; g < 64; ++g) {
    int j = g >> 2;
    // stage NEXT group's 4 B taps into buf (g+1)&1 (read last at group g-1;
    // all waves passed the end-of-(g-1) barrier -> write-safe)
    if (g < 63) {
      const f16* src = gBm + (size_t)(g + 1) * 4 * 32768;
      f16* dst = bD0 + ((g + 1) & 1) * 8192;
#pragma unroll
      for (int t = 0; t < 4; ++t) gl2lds16(src + (size_t)t * 32768, dst + t * 2048);
    }
    // compute group g: taps k = (g&3)*4 .. +3, from Asl and Bb[g&1]
    const f16* Bc = Bb + (g & 1) * 8192;
#pragma unroll
    for (int t = 0; t < 4; ++t) {
      int k = ((g & 3) << 2) + t;
      // A frag: slab row = k + wave*128 + i*16 + fr ; swizzle incl. tap offset k
      // (wave*128 and i*16 are multiples of 8 -> don't affect (row>>1)&3).
      int aswz = ((k + fr) >> 1) & 3;
      const f16* ap = Asl + (size_t)(k + wave * 128 + fr) * 32 + ((q ^ aswz) << 3);
      f16x8 bf[4];
#pragma unroll
      for (int jj = 0; jj < 4; ++jj)
        bf[jj] = *(const f16x8*)(Bc + t * 2048 + (jj * 16 + fr) * 32 + fqB);
#pragma unroll
      for (int i = 0; i < 8; ++i) {
        f16x8 af = *(const f16x8*)(ap + i * 512);
#pragma unroll
        for (int jj = 0; jj < 4; ++jj)
          acc[i][jj] = __builtin_amdgcn_mfma_f32_16x16x32_f16(af, bf[jj], acc[i][jj], 0, 0, 0);
      }
    }
    __syncthreads();   // vmcnt(0): B(g+1) landed (issued one full group ago);
                       // all waves done reading Asl/Bb[g&1].
    // j boundary: restage A for j+1 (A is single-buffered; waves just finished
    // the last taps of j and passed the barrier above)
    if ((g & 3) == 3 && j < 15) {
#pragma unroll
      for (int c = 0; c < 8; ++c) gl2lds16(gAm[c] + (j + 1) * 32, aD0 + c * 2048);
      gl2lds16(gAt + (j + 1) * 32, Asl + 16384);
      __syncthreads();  // drain A(j+1) (L2-warm via mb pinning) before its first read
    }
  }

  // epilogue: bias + relu + f16 store. C/D: col=lane&15 (n), row=(lane>>4)*4+reg (m)
  int col = lane & 15, rq = (lane >> 4) << 2;
  int mbase = m0 + wave * 128 + rq;
  int nbase = n0 + col;
#pragma unroll
  for (int jj = 0; jj < 4; ++jj) {
    int h = nbase + jj * 16;
    float bias = cb[h];
#pragma unroll
    for (int i = 0; i < 8; ++i) {
      int m = mbase + i * 16;
#pragma unroll
      for (int rg = 0; rg < 4; ++rg) {
        float v = acc[i][jj][rg] + bias;
        v = v > 0.f ? v : 0.f;
        cout[(size_t)(m + rg) * 1024 + h] = (f16)v;
      }
    }
  }
}

// ---------------- linear GEMM [65536 x 1536] x [1536 x 256] + fused softmax ----------
__global__ __launch_bounds__(256) void k_lin(const f16* __restrict__ embp,
                                             const f16* __restrict__ cout,
                                             const f16* __restrict__ lt2,
                                             const float* __restrict__ lb,
                                             float* __restrict__ out) {
  __shared__ __align__(16) char smem[32 * 261 * 4];  // Ls overlays As|Bs
  __shared__ float pmax[4][32], psum[4][32], mrow[32], rinv[32];
  f16* As = (f16*)smem;             // [64][32]   4 KB
  f16* Bs = (f16*)(smem + 4096);    // [256][32] 16 KB
  float* Ls = (float*)smem;         // [32][261] f32 epilogue logits
  int m0 = blockIdx.x << 6;
  int b = m0 >> 11, t0 = m0 & 2047;
  int tid = threadIdx.x, lane = tid & 63, wave = tid >> 6;
  int sr = lane >> 2, sc = (lane & 3) << 3;
  const f16* gAe = embp + (size_t)(b * SP + 15 + t0 + wave * 16 + sr) * 512 + sc;
  const f16* gAc = cout + (size_t)(m0 + wave * 16 + sr) * 1024 + sc;
  f16* lA = As + wave * 512;
  int fr = lane & 15, fq = (lane >> 4) << 3;
  f32x4 zero = {0.f, 0.f, 0.f, 0.f};
  f32x4 acc[4][4];
#pragma unroll
  for (int i = 0; i < 4; ++i)
#pragma unroll
    for (int j = 0; j < 4; ++j) acc[i][j] = zero;

  for (int kb = 0; kb < 48; ++kb) {
    if (kb < 16) gl2lds16(gAe + kb * 32, lA);
    else         gl2lds16(gAc + (kb - 16) * 32, lA);
#pragma unroll
    for (int jj = 0; jj < 4; ++jj) {
      int c = wave * 4 + jj;
      gl2lds16(lt2 + (size_t)kb * 8192 + (c * 16 + sr) * 32 + sc, Bs + c * 512);
    }
    __syncthreads();
    f16x8 af[4], bf[4];
#pragma unroll
    for (int i = 0; i < 4; ++i)
      af[i] = *(const f16x8*)(As + (i * 16 + fr) * 32 + fq);
#pragma unroll
    for (int j = 0; j < 4; ++j)
      bf[j] = *(const f16x8*)(Bs + (wave * 64 + j * 16 + fr) * 32 + fq);
#pragma unroll
    for (int i = 0; i < 4; ++i)
#pragma unroll
      for (int j = 0; j < 4; ++j)
        acc[i][j] = __builtin_amdgcn_mfma_f32_16x16x32_f16(af[i], bf[j], acc[i][j], 0, 0, 0);
    __syncthreads();
  }

  // softmax epilogue, two 32-row halves. Ls stride 261 (coprime with 32).
  int col = lane & 15, rq = (lane >> 4) << 2;
  for (int hf = 0; hf < 2; ++hf) {
    __syncthreads();
#pragma unroll
    for (int j = 0; j < 4; ++j) {
      int v = wave * 64 + j * 16 + col;
      float bias = lb[v];
#pragma unroll
      for (int i = 0; i < 2; ++i) {
        int rloc = i * 16 + rq;
        int ig = hf * 2 + i;
#pragma unroll
        for (int rg = 0; rg < 4; ++rg)
          Ls[(rloc + rg) * 261 + v] = acc[ig][j][rg] + bias;
      }
    }
    __syncthreads();
    if (tid < 128) {
      int r = tid & 31, qd = tid >> 5;
      const float* rowp = Ls + r * 261 + qd * 64;
      float pm = -1e30f;
#pragma unroll 8
      for (int c = 0; c < 64; ++c) pm = fmaxf(pm, rowp[c]);
      pmax[qd][r] = pm;
    }
    __syncthreads();
    if (tid < 32)
      mrow[tid] = fmaxf(fmaxf(pmax[0][tid], pmax[1][tid]), fmaxf(pmax[2][tid], pmax[3][tid]));
    __syncthreads();
    if (tid < 128) {
      int r = tid & 31, qd = tid >> 5;
      const float* rowp = Ls + r * 261 + qd * 64;
      float mr = mrow[r], ps = 0.f;
#pragma unroll 8
      for (int c = 0; c < 64; ++c) ps += __expf(rowp[c] - mr);
      psum[qd][r] = ps;
    }
    __syncthreads();
    if (tid < 32)
      rinv[tid] = 1.f / (psum[0][tid] + psum[1][tid] + psum[2][tid] + psum[3][tid]);
    __syncthreads();
    float* obase = out + (size_t)(m0 + hf * 32) * 256 + tid;
#pragma unroll 4
    for (int r = 0; r < 32; ++r)
      obase[(size_t)r * 256] = __expf(Ls[r * 261 + tid] - mrow[r]) * rinv[r];
  }
}

extern "C" void kernel_launch(void* const* d_in, const int* in_sizes, int n_in,
                              void* d_out, int out_size, void* d_ws, size_t ws_size,
                              hipStream_t stream) {
  const int*   seq = (const int*)d_in[0];
  const float* tab = (const float*)d_in[1];
  const float* cw  = (const float*)d_in[2];
  const float* cb  = (const float*)d_in[3];
  const float* lw  = (const float*)d_in[4];
  const float* lb  = (const float*)d_in[5];
  float* out = (float*)d_out;
  char* ws = (char*)d_ws;
  // workspace layout (needs ~219.4 MB):
  f16* embp = (f16*)(ws);               //  67,600,384 B  [32*2063][512]
  f16* cout = (f16*)(ws + 67600384);    // 134,217,728 B  [65536][1024]
  f16* wt2  = (f16*)(ws + 201818112);   //  16,777,216 B  [256 jk][1024 h][32 e5]
  f16* lt2  = (f16*)(ws + 218595328);   //     786,432 B  [48][256][32]

  hipLaunchKernelGGL(k_gather, dim3(16504), dim3(256), 0, stream, seq, tab, embp);
  hipLaunchKernelGGL(k_twc,    dim3(1024),  dim3(256), 0, stream, cw, wt2);
  hipLaunchKernelGGL(k_twl,    dim3(1536),  dim3(256), 0, stream, lw, lt2);
  hipLaunchKernelGGL(k_conv,   dim3(2048),  dim3(256), 0, stream, embp, wt2, cb, cout);
  hipLaunchKernelGGL(k_lin,    dim3(1024),  dim3(256), 0, stream, embp, cout, lt2, lb, out);
}